// Round 19
// baseline (677.325 us; speedup 1.0000x reference)
//
#include <hip/hip_runtime.h>
#include <cstdint>

// Problem constants
#define BB 4
#define NN 16384
#define CC 512
#define HH 16
#define DD 32
#define HID 2048
#define MTOT (BB * NN)        // 65536 tokens

typedef __bf16 bf16_t;
typedef __bf16 bf16x8 __attribute__((ext_vector_type(8)));
typedef __bf16 bf16x4 __attribute__((ext_vector_type(4)));
typedef float  f32x4  __attribute__((ext_vector_type(4)));
typedef float  f32x16 __attribute__((ext_vector_type(16)));

// ---- async global->LDS 16B ----
__device__ __forceinline__ void gload_lds16(const void* g, void* l) {
  auto gp = reinterpret_cast<const __attribute__((address_space(1))) char*>(
      reinterpret_cast<uintptr_t>(g));
  auto lp = reinterpret_cast<__attribute__((address_space(3))) char*>(
      reinterpret_cast<uintptr_t>(l));
  __builtin_amdgcn_global_load_lds(gp, lp, 16, 0, 0);
}

// ---- fp32 -> bf16 weight convert ----
__global__ __launch_bounds__(256) void cvt_bf16_kernel(const float* __restrict__ src,
                                                       bf16_t* __restrict__ dst) {
  const long i = ((long)blockIdx.x * 256 + threadIdx.x) * 4;
  const f32x4 v = *(const f32x4*)(src + i);
  bf16x4 o;
  o[0] = (bf16_t)v[0]; o[1] = (bf16_t)v[1]; o[2] = (bf16_t)v[2]; o[3] = (bf16_t)v[3];
  *(bf16x4*)(dst + i) = o;
}

// ---- LayerNorm1: one wave per token; lane owns 8 contiguous channels ----
__global__ __launch_bounds__(256) void norm1_kernel(const float* __restrict__ x,
                                                    const float* __restrict__ w,
                                                    const float* __restrict__ bvec,
                                                    bf16_t* __restrict__ h) {
  const int wv = threadIdx.x >> 6, l = threadIdx.x & 63;
  const long tok = (long)blockIdx.x * 4 + wv;
  const int c0 = l * 8;
  const f32x4 a = *(const f32x4*)(x + tok * CC + c0);
  const f32x4 b = *(const f32x4*)(x + tok * CC + c0 + 4);
  float v[8];
#pragma unroll
  for (int i = 0; i < 4; ++i) { v[i] = a[i]; v[4 + i] = b[i]; }
  float s = 0.f, s2 = 0.f;
#pragma unroll
  for (int i = 0; i < 8; ++i) { s += v[i]; s2 += v[i] * v[i]; }
  for (int off = 32; off; off >>= 1) { s += __shfl_xor(s, off); s2 += __shfl_xor(s2, off); }
  const float mean = s * (1.f / CC);
  const float var  = fmaxf(s2 * (1.f / CC) - mean * mean, 0.f);
  const float rstd = rsqrtf(var + 1e-5f);
  const f32x4 w0 = *(const f32x4*)(w + c0), w1 = *(const f32x4*)(w + c0 + 4);
  const f32x4 b0 = *(const f32x4*)(bvec + c0), b1 = *(const f32x4*)(bvec + c0 + 4);
  bf16x8 o;
#pragma unroll
  for (int i = 0; i < 4; ++i) {
    o[i]     = (bf16_t)(w0[i] * (v[i] - mean) * rstd + b0[i]);
    o[4 + i] = (bf16_t)(w1[i] * (v[4 + i] - mean) * rstd + b1[i]);
  }
  *(bf16x8*)(h + tok * CC + c0) = o;
}

// ---- kv partial: block = (b,head,chunk of 256 tokens) ----
__global__ __launch_bounds__(256) void kv_partial_kernel(const bf16_t* __restrict__ h,
                                                         const float* __restrict__ klw,
                                                         const float* __restrict__ klb,
                                                         const float* __restrict__ vlw,
                                                         const float* __restrict__ vlb,
                                                         float* __restrict__ kvp) {
  __shared__ bf16_t kb[256 * 32];
  __shared__ bf16_t vb[256 * 32];
  __shared__ float scratch[192 * 16];   // 12KB
  const int tid = threadIdx.x;
  const int bh = blockIdx.x >> 6, chunk = blockIdx.x & 63;
  const int head = bh & 15;
  const int b = bh >> 4;
  const long tok0 = ((long)b << 14) + chunk * 256;
  const bf16_t* src = h + (tok0 + tid) * (long)CC + head * DD;
  float hv[32];
  {
    float s = 0.f, s2 = 0.f;
#pragma unroll
    for (int c = 0; c < 4; ++c) {
      const bf16x8 r = *(const bf16x8*)(src + c * 8);
#pragma unroll
      for (int j = 0; j < 8; ++j) {
        hv[c * 8 + j] = (float)r[j]; s += hv[c * 8 + j]; s2 += hv[c * 8 + j] * hv[c * 8 + j];
      }
    }
    const float mean = s * (1.f / 32.f);
    const float varu = fmaxf((s2 - 32.f * mean * mean) * (1.f / 31.f), 0.f);
    const float inv = 1.f / (sqrtf(varu) + 1e-5f);   // torch.std semantics
    const int sx = (tid >> 1) & 3;
#pragma unroll
    for (int c = 0; c < 4; ++c) {
      bf16x8 kc, vc;
#pragma unroll
      for (int j = 0; j < 8; ++j) {
        const int d = c * 8 + j;
        const float t = (hv[d] - mean) * inv;
        kc[j] = (bf16_t)(klw[head * DD + d] * t + klb[head * DD + d]);
        vc[j] = (bf16_t)(vlw[head * DD + d] * t + vlb[head * DD + d]);
      }
      *(bf16x8*)((char*)kb + tid * 64 + ((c ^ sx) * 16)) = kc;
      *(bf16x8*)((char*)vb + tid * 64 + ((c ^ sx) * 16)) = vc;
    }
  }
  __syncthreads();
  const int g = tid >> 6, l = tid & 63;
  const int d0 = (l >> 3) * 4, e0 = (l & 7) * 4;
  const int ck = (l >> 3) >> 1, hk = (l >> 3) & 1;
  const int ce = (l & 7) >> 1, he = l & 1;
  float a[4][4] = {};
  for (int t = g; t < 256; t += 4) {
    const int tx = (t >> 1) & 3;
    const bf16x4 kq = *(const bf16x4*)((const char*)kb + t * 64 + ((ck ^ tx) * 16) + hk * 8);
    const bf16x4 vq = *(const bf16x4*)((const char*)vb + t * 64 + ((ce ^ tx) * 16) + he * 8);
    float kf[4], vf[4];
#pragma unroll
    for (int i2 = 0; i2 < 4; ++i2) { kf[i2] = (float)kq[i2]; vf[i2] = (float)vq[i2]; }
#pragma unroll
    for (int i2 = 0; i2 < 4; ++i2)
#pragma unroll
      for (int j2 = 0; j2 < 4; ++j2) a[i2][j2] += kf[i2] * vf[j2];
  }
  __syncthreads();
  if (g) {
#pragma unroll
    for (int i2 = 0; i2 < 4; ++i2)
#pragma unroll
      for (int j2 = 0; j2 < 4; ++j2)
        scratch[((g - 1) * 64 + l) * 16 + i2 * 4 + j2] = a[i2][j2];
  }
  __syncthreads();
  if (!g) {
#pragma unroll
    for (int gg = 0; gg < 3; ++gg)
#pragma unroll
      for (int i2 = 0; i2 < 4; ++i2)
#pragma unroll
        for (int j2 = 0; j2 < 4; ++j2)
          a[i2][j2] += scratch[(gg * 64 + l) * 16 + i2 * 4 + j2];
    float* dst = kvp + ((long)(bh * 64 + chunk) << 10);
#pragma unroll
    for (int i2 = 0; i2 < 4; ++i2) {
      f32x4 st;
      st[0] = a[i2][0]; st[1] = a[i2][1]; st[2] = a[i2][2]; st[3] = a[i2][3];
      *(f32x4*)&dst[(d0 + i2) * 32 + e0] = st;
    }
  }
}

// ---- kv reduce over 64 chunks, /N, store TRANSPOSED bf16: kvT[bh][e][d] ----
__global__ __launch_bounds__(256) void kv_reduce_kernel(const float* __restrict__ kvp,
                                                        bf16_t* __restrict__ kvT) {
  const int bh = blockIdx.x;
  const int i4 = threadIdx.x * 4;
  const int d = i4 >> 5, e0 = i4 & 31;
  float s[4] = {};
  const float* p = kvp + ((long)bh << 16) + i4;
  for (int ch = 0; ch < 64; ++ch) {
    const f32x4 t = *(const f32x4*)(p + (ch << 10));
    s[0] += t[0]; s[1] += t[1]; s[2] += t[2]; s[3] += t[3];
  }
  const float sc = 1.f / (float)NN;
  bf16_t* q = kvT + ((long)bh << 10);
#pragma unroll
  for (int j = 0; j < 4; ++j) q[(e0 + j) * 32 + d] = (bf16_t)(s[j] * sc);
}

// ---- fused: MFMA attn + residuals -> x2 (bf16 to ws), LN2 -> m (bf16) ----
// Phase 2: deep preload (two 4-iteration batches of x/h loads in flight).
#define ASTRIDE 520
__global__ __launch_bounds__(256) void attn_fused_kernel(const float* __restrict__ x,
                                                         const bf16_t* __restrict__ h,
                                                         const bf16_t* __restrict__ kvTg,
                                                         const float* __restrict__ n2w,
                                                         const float* __restrict__ n2b,
                                                         bf16_t* __restrict__ x2b,
                                                         bf16_t* __restrict__ mout) {
  __shared__ bf16_t attn_s[32 * ASTRIDE];
  const int tid = threadIdx.x;
  const int wv = tid >> 6, lane = tid & 63;
  const int lr = lane & 15, kg = lane >> 4;
  const long tok0 = (long)blockIdx.x * 32;
  const int b = (int)(tok0 >> 14);
  const bf16_t* kvsrc = kvTg + ((long)b << 14);

  {
    const int tt = wv & 1, hh = wv >> 1;
    const bf16_t* arow = h + (tok0 + tt * 16 + lr) * (long)CC + kg * 8;
    const f32x4 zero = {};
#pragma unroll
    for (int hi = 0; hi < 8; ++hi) {
      const int hd = hh * 8 + hi;
      const bf16_t* kvh = kvsrc + (hd << 10) + kg * 8;
      const bf16x8 af = *(const bf16x8*)(arow + hd * DD);
      const bf16x8 b0 = *(const bf16x8*)(kvh + lr * 32);
      const bf16x8 b1 = *(const bf16x8*)(kvh + (16 + lr) * 32);
      const f32x4 a0 = __builtin_amdgcn_mfma_f32_16x16x32_bf16(af, b0, zero, 0, 0, 0);
      const f32x4 a1 = __builtin_amdgcn_mfma_f32_16x16x32_bf16(af, b1, zero, 0, 0, 0);
      const int rbase = tt * 16 + kg * 4;
#pragma unroll
      for (int rg = 0; rg < 4; ++rg) {
        attn_s[(rbase + rg) * ASTRIDE + hd * 32 + lr]      = (bf16_t)a0[rg];
        attn_s[(rbase + rg) * ASTRIDE + hd * 32 + 16 + lr] = (bf16_t)a1[rg];
      }
    }
  }

  const int c0 = lane * 8;
  const f32x4 w0 = *(const f32x4*)(n2w + c0), w1 = *(const f32x4*)(n2w + c0 + 4);
  const f32x4 bb0 = *(const f32x4*)(n2b + c0), bb1 = *(const f32x4*)(n2b + c0 + 4);
  const long tokb = tok0 + wv * 8;

  // batch A: iterations 0..3 (independent of attn_s) before the barrier
  f32x4 xaA[4], xbA[4];
  bf16x8 hvA[4];
#pragma unroll
  for (int it = 0; it < 4; ++it) {
    xaA[it] = *(const f32x4*)(x + (tokb + it) * CC + c0);
    xbA[it] = *(const f32x4*)(x + (tokb + it) * CC + c0 + 4);
    hvA[it] = *(const bf16x8*)(h + (tokb + it) * CC + c0);
  }
  __syncthreads();
  // batch B: iterations 4..7 issued now; retire under batch-A compute
  f32x4 xaB[4], xbB[4];
  bf16x8 hvB[4];
#pragma unroll
  for (int it = 0; it < 4; ++it) {
    xaB[it] = *(const f32x4*)(x + (tokb + 4 + it) * CC + c0);
    xbB[it] = *(const f32x4*)(x + (tokb + 4 + it) * CC + c0 + 4);
    hvB[it] = *(const bf16x8*)(h + (tokb + 4 + it) * CC + c0);
  }

#pragma unroll
  for (int it = 0; it < 8; ++it) {
    const f32x4 xa = (it < 4) ? xaA[it] : xaB[it - 4];
    const f32x4 xb = (it < 4) ? xbA[it] : xbB[it - 4];
    const bf16x8 hv = (it < 4) ? hvA[it] : hvB[it - 4];
    const int tl = wv * 8 + it;
    const long tok = tok0 + tl;
    const bf16x8 av = *(const bf16x8*)&attn_s[tl * ASTRIDE + c0];
    float x2[8];
#pragma unroll
    for (int i = 0; i < 4; ++i) {
      x2[i]     = xa[i] + (float)hv[i]     + (float)av[i];
      x2[4 + i] = xb[i] + (float)hv[4 + i] + (float)av[4 + i];
    }
    float s = 0.f, s2 = 0.f;
#pragma unroll
    for (int i = 0; i < 8; ++i) { s += x2[i]; s2 += x2[i] * x2[i]; }
    for (int off = 32; off; off >>= 1) { s += __shfl_xor(s, off); s2 += __shfl_xor(s2, off); }
    const float mean = s * (1.f / CC);
    const float var  = fmaxf(s2 * (1.f / CC) - mean * mean, 0.f);
    const float rstd = rsqrtf(var + 1e-5f);
    bf16x8 ox, om;
#pragma unroll
    for (int i = 0; i < 4; ++i) {
      ox[i]     = (bf16_t)x2[i];
      ox[4 + i] = (bf16_t)x2[4 + i];
      om[i]     = (bf16_t)(w0[i] * (x2[i] - mean) * rstd + bb0[i]);
      om[4 + i] = (bf16_t)(w1[i] * (x2[4 + i] - mean) * rstd + bb1[i]);
    }
    *(bf16x8*)(x2b + tok * CC + c0) = ox;
    *(bf16x8*)(mout + tok * CC + c0) = om;
  }
}

// ---- dual-role 8-phase GEMM (r16 schedule, 32x32x16 MFMA, BN=256) ----
// blocks [0, g1blocks) run GEMM1 (K=512 -> HID, GELU -> bf16 act);
// blocks [g1blocks, grid) run GEMM2 (K=2048 -> CC, +x2b -> fp32 out).
// Both roles independent within a dispatch (separate act buffers across
// dispatches); overlap smooths MFMA-heavy vs HBM-heavy phases across CUs.
__global__ __launch_bounds__(512, 2) void gemm_dual_kernel(
    const bf16_t* __restrict__ A1, const bf16_t* __restrict__ B1w,
    const float* __restrict__ bias1, bf16_t* __restrict__ out1b,
    const bf16_t* __restrict__ A2, const bf16_t* __restrict__ B2w,
    const float* __restrict__ bias2, float* __restrict__ out2f,
    const bf16_t* __restrict__ x2b, int g1blocks) {
  constexpr int BN = 256;
  constexpr int WNSPAN = 64;
  constexpr int NF2 = 2;
  constexpr int ABYT = 32768;
  constexpr int BBYT = BN * 128;
  constexpr int BUFB = ABYT + BBYT;          // 64KB
  constexpr int KSB = BN * 64;               // 16384

  __shared__ char lds[2 * BUFB];             // 128KB

  const int tid = threadIdx.x;
  const int wid = tid >> 6, lane = tid & 63;
  const int wm = wid >> 2, wn = wid & 3;
  const int l31 = lane & 31, kg5 = lane >> 5;

  const bool role1 = ((int)blockIdx.x < g1blocks);
  const int rblocks = role1 ? g1blocks : ((int)gridDim.x - g1blocks);
  int bid = role1 ? (int)blockIdx.x : ((int)blockIdx.x - g1blocks);
  const int K     = role1 ? CC : HID;
  const long NOUT = role1 ? HID : CC;
  const int NTILE = role1 ? (HID / BN) : (CC / BN);
  const int NT    = K / 64;
  const int NI    = NT / 2;
  const bf16_t* A    = role1 ? A1 : A2;
  const bf16_t* Bw   = role1 ? B1w : B2w;
  const float*  bias = role1 ? bias1 : bias2;

  const int qq = rblocks >> 3;
  bid = (bid & 7) * qq + (bid >> 3);        // XCD swizzle (rblocks % 8 == 0)
  const long row0 = (long)(bid / NTILE) * 256;
  const long col0 = (long)(bid % NTILE) * BN;

  const int srow = tid >> 2;                                   // 0..127
  const int ssw = (((srow >> 1) & 3) ^ ((srow >> 3) & 3));     // enriched swizzle
  const int sce = (((tid & 3) ^ ssw) << 3);                    // pre-swizzled col
  const bf16_t* pA = A + (row0 + srow) * (long)K + sce;
  const bf16_t* pB = Bw + (col0 + srow) * (long)K + sce;
  char* ldsp = (char*)lds;

  auto SA = [&](int buf, int ks, int kt) {
    char* d_ = ldsp + buf * BUFB + ks * 16384 + tid * 16;
    const bf16_t* g_ = pA + (long)kt * 64 + ks * 32;
    gload_lds16(g_, d_);
    gload_lds16(g_ + 128L * K, d_ + 8192);
  };
  auto SB = [&](int buf, int ks, int kt) {
    char* d_ = ldsp + buf * BUFB + ABYT + ks * KSB + tid * 16;
    const bf16_t* g_ = pB + (long)kt * 64 + ks * 32;
    gload_lds16(g_, d_);
    gload_lds16(g_ + 128L * K, d_ + 8192);
  };

  f32x16 acc[4][NF2] = {};
  bf16x8 af[4], bf[NF2];

  const int swz = ((l31 >> 1) & 3) ^ ((l31 >> 3) & 3);
  const int cb0 = (((0 << 1) | kg5) ^ swz) << 4;
  const int cb1 = (((1 << 1) | kg5) ^ swz) << 4;
  const char* aR = ldsp + (wm * 128 + l31) * 64;
  const char* bR = ldsp + ABYT + (wn * WNSPAN + l31) * 64;

  auto RD = [&](int buf, int ks, int k16) {
    const int cb = k16 ? cb1 : cb0;
    const char* a_ = aR + buf * BUFB + ks * 16384 + cb;
    const char* b_ = bR + buf * BUFB + ks * KSB + cb;
#pragma unroll
    for (int mf = 0; mf < 4; ++mf) af[mf] = *(const bf16x8*)(a_ + mf * 2048);
#pragma unroll
    for (int nf = 0; nf < NF2; ++nf) bf[nf] = *(const bf16x8*)(b_ + nf * 2048);
  };
  auto MM = [&]() {
    __builtin_amdgcn_s_setprio(1);
#pragma unroll
    for (int mf = 0; mf < 4; ++mf)
#pragma unroll
      for (int nf = 0; nf < NF2; ++nf)
        acc[mf][nf] =
            __builtin_amdgcn_mfma_f32_32x32x16_bf16(af[mf], bf[nf], acc[mf][nf], 0, 0, 0);
    __builtin_amdgcn_s_setprio(0);
  };
#define W2U() asm volatile("s_waitcnt vmcnt(8)" ::: "memory")
#define W1U() asm volatile("s_waitcnt vmcnt(4)" ::: "memory")
#define BARX() __builtin_amdgcn_s_barrier()
#define LGKM0() asm volatile("s_waitcnt lgkmcnt(0)" ::: "memory")
#define W0U() asm volatile("s_waitcnt vmcnt(0)" ::: "memory")

  // prologue: stage 3 units in consumption order; land unit 1 only
  SA(0, 0, 0); SB(0, 0, 0);
  SA(0, 1, 0); SB(0, 1, 0);
  SA(1, 0, 1); SB(1, 0, 1);
  W2U();
  BARX();

  for (int i = 0; i < NI; ++i) {
    const int t1 = 2 * i + 1, tA = 2 * i + 2, tB = 2 * i + 3;
    // p1: read b0.ks0.k0 | stage b1k1.A
    RD(0, 0, 0); SA(1, 1, t1);
    BARX(); LGKM0(); MM(); BARX();
    // p2: read b0.ks0.k1 | stage b1k1.B | wait lands b0k1 (for p3/p4)
    RD(0, 0, 1); SB(1, 1, t1);
    BARX(); LGKM0(); MM(); W2U(); BARX();
    // p3: read b0.ks1.k0 | stage next b0k0.A
    RD(0, 1, 0); if (tA < NT) SA(0, 0, tA);
    BARX(); LGKM0(); MM(); BARX();
    // p4: read b0.ks1.k1 | stage next b0k0.B | wait lands b1k0 (for p5/p6)
    RD(0, 1, 1); if (tA < NT) SB(0, 0, tA);
    BARX(); LGKM0(); MM();
    if (tA < NT) W2U(); else W1U();
    BARX();
    // p5: read b1.ks0.k0 | stage next b0k1.A
    RD(1, 0, 0); if (tA < NT) SA(0, 1, tA);
    BARX(); LGKM0(); MM(); BARX();
    // p6: read b1.ks0.k1 | stage next b0k1.B | wait lands b1k1 (for p7/p8)
    RD(1, 0, 1); if (tA < NT) SB(0, 1, tA);
    BARX(); LGKM0(); MM();
    if (tA < NT) W2U(); else W0U();
    BARX();
    // p7: read b1.ks1.k0 | stage next b1k0.A
    RD(1, 1, 0); if (tB < NT) SA(1, 0, tB);
    BARX(); LGKM0(); MM(); BARX();
    // p8: read b1.ks1.k1 | stage next b1k0.B | wait lands next b0k0
    RD(1, 1, 1); if (tB < NT) SB(1, 0, tB);
    BARX(); LGKM0(); MM();
    if (tB < NT) W2U();
    BARX();
  }
#undef W2U
#undef W1U
#undef BARX
#undef LGKM0
#undef W0U

  // epilogue: 32x32 C/D layout: col = l31, row = (r&3) + 8*(r>>2) + 4*kg5
#pragma unroll
  for (int mf = 0; mf < 4; ++mf) {
#pragma unroll
    for (int nf = 0; nf < NF2; ++nf) {
      const long col = col0 + wn * WNSPAN + nf * 32 + l31;
      const float bs = bias[col];
#pragma unroll
      for (int r = 0; r < 16; ++r) {
        const long row = row0 + wm * 128 + mf * 32 + (r & 3) + 8 * (r >> 2) + 4 * kg5;
        const float v = acc[mf][nf][r] + bs;
        if (role1) {
          const float u = 0.7978845608028654f * (v + 0.044715f * v * v * v);
          const float gv = v / (1.f + __expf(-2.f * u));
          out1b[row * NOUT + col] = (bf16_t)gv;
        } else {
          out2f[row * NOUT + col] = (float)x2b[row * NOUT + col] + v;
        }
      }
    }
  }
}

extern "C" void kernel_launch(void* const* d_in, const int* in_sizes, int n_in,
                              void* d_out, int out_size, void* d_ws, size_t ws_size,
                              hipStream_t stream) {
  const float* x   = (const float*)d_in[0];
  const float* n1w = (const float*)d_in[2];
  const float* n1b = (const float*)d_in[3];
  const float* klw = (const float*)d_in[4];
  const float* klb = (const float*)d_in[5];
  const float* vlw = (const float*)d_in[6];
  const float* vlb = (const float*)d_in[7];
  const float* n2w = (const float*)d_in[8];
  const float* n2b = (const float*)d_in[9];
  const float* w1f = (const float*)d_in[10];
  const float* b1  = (const float*)d_in[11];
  const float* w2f = (const float*)d_in[12];
  const float* b2  = (const float*)d_in[13];
  float* out = (float*)d_out;

  // choose chunking / act buffering from workspace size
  // base = h+mb+x2b (192MiB) + weights 4MiB + kvp 16MiB + kvT = 212.2 MiB
  int nch; bool dual;
  if (ws_size >= 470000000ULL)      { nch = 2; dual = true;  }  // 2x128MiB act
  else if (ws_size >= 357000000ULL) { nch = 4; dual = true;  }  // 2x64MiB act
  else if (ws_size >= 290000000ULL) { nch = 8; dual = true;  }  // 2x32MiB act
  else                              { nch = 8; dual = false; }  // 1x32MiB act
  const long mch = MTOT / nch;

  char* ws = (char*)d_ws;
  size_t off = 0;
  bf16_t* h    = (bf16_t*)(ws + off); off += (size_t)MTOT * CC * 2;     // 64 MiB
  bf16_t* mb   = (bf16_t*)(ws + off); off += (size_t)MTOT * CC * 2;     // 64 MiB
  bf16_t* x2b  = (bf16_t*)(ws + off); off += (size_t)MTOT * CC * 2;     // 64 MiB
  bf16_t* act0 = (bf16_t*)(ws + off); off += (size_t)mch * HID * 2;
  bf16_t* act1 = act0;
  if (dual) { act1 = (bf16_t*)(ws + off); off += (size_t)mch * HID * 2; }
  bf16_t* w1  = (bf16_t*)(ws + off); off += (size_t)HID * CC * 2;       // 2 MiB
  bf16_t* w2  = (bf16_t*)(ws + off); off += (size_t)HID * CC * 2;       // 2 MiB
  float*  kvp = (float*)(ws + off);  off += (size_t)BB * HH * 64 * 1024 * 4; // 16 MiB
  bf16_t* kvT = (bf16_t*)(ws + off);                                    // 128 KiB
  bf16_t* acts[2] = {act0, act1};

  cvt_bf16_kernel<<<1024, 256, 0, stream>>>(w1f, w1);
  cvt_bf16_kernel<<<1024, 256, 0, stream>>>(w2f, w2);
  norm1_kernel<<<MTOT / 4, 256, 0, stream>>>(x, n1w, n1b, h);
  kv_partial_kernel<<<BB * HH * 64, 256, 0, stream>>>(h, klw, klb, vlw, vlb, kvp);
  kv_reduce_kernel<<<BB * HH, 256, 0, stream>>>(kvp, kvT);
  attn_fused_kernel<<<MTOT / 32, 256, 0, stream>>>(x, h, kvT, n2w, n2b, x2b, mb);

  const int g1grid = (int)((mch / 256) * (HID / 256));
  const int g2grid = (int)((mch / 256) * (CC / 256));

  if (dual) {
    // d0: GEMM1(ch0) only
    gemm_dual_kernel<<<g1grid, 512, 0, stream>>>(
        mb, w1, b1, acts[0],
        acts[0], w2, b2, out, x2b, g1grid);
    // middle: GEMM1(ch i) || GEMM2(ch i-1)
    for (int i = 1; i < nch; ++i) {
      gemm_dual_kernel<<<g1grid + g2grid, 512, 0, stream>>>(
          mb + (size_t)i * mch * CC, w1, b1, acts[i & 1],
          acts[(i - 1) & 1], w2, b2, out + (size_t)(i - 1) * mch * CC,
          x2b + (size_t)(i - 1) * mch * CC, g1grid);
    }
    // last: GEMM2(ch nch-1) only
    gemm_dual_kernel<<<g2grid, 512, 0, stream>>>(
        mb, w1, b1, acts[0],
        acts[(nch - 1) & 1], w2, b2, out + (size_t)(nch - 1) * mch * CC,
        x2b + (size_t)(nch - 1) * mch * CC, 0);
  } else {
    for (int i = 0; i < nch; ++i) {
      gemm_dual_kernel<<<g1grid, 512, 0, stream>>>(
          mb + (size_t)i * mch * CC, w1, b1, acts[0],
          acts[0], w2, b2, out, x2b, g1grid);
      gemm_dual_kernel<<<g2grid, 512, 0, stream>>>(
          mb, w1, b1, acts[0],
          acts[0], w2, b2, out + (size_t)i * mch * CC,
          x2b + (size_t)i * mch * CC, 0);
    }
  }
}

// Round 20
// 572.888 us; speedup vs baseline: 1.1823x; 1.1823x over previous
//
#include <hip/hip_runtime.h>
#include <cstdint>

// Problem constants
#define BB 4
#define NN 16384
#define CC 512
#define HH 16
#define DD 32
#define HID 2048
#define MTOT (BB * NN)        // 65536 tokens

typedef __bf16 bf16_t;
typedef __bf16 bf16x8 __attribute__((ext_vector_type(8)));
typedef __bf16 bf16x4 __attribute__((ext_vector_type(4)));
typedef float  f32x4  __attribute__((ext_vector_type(4)));
typedef float  f32x16 __attribute__((ext_vector_type(16)));

// ---- async global->LDS 16B ----
__device__ __forceinline__ void gload_lds16(const void* g, void* l) {
  auto gp = reinterpret_cast<const __attribute__((address_space(1))) char*>(
      reinterpret_cast<uintptr_t>(g));
  auto lp = reinterpret_cast<__attribute__((address_space(3))) char*>(
      reinterpret_cast<uintptr_t>(l));
  __builtin_amdgcn_global_load_lds(gp, lp, 16, 0, 0);
}

// ---- fp32 -> bf16 weight convert ----
__global__ __launch_bounds__(256) void cvt_bf16_kernel(const float* __restrict__ src,
                                                       bf16_t* __restrict__ dst) {
  const long i = ((long)blockIdx.x * 256 + threadIdx.x) * 4;
  const f32x4 v = *(const f32x4*)(src + i);
  bf16x4 o;
  o[0] = (bf16_t)v[0]; o[1] = (bf16_t)v[1]; o[2] = (bf16_t)v[2]; o[3] = (bf16_t)v[3];
  *(bf16x4*)(dst + i) = o;
}

// ---- LayerNorm1: one wave per token; lane owns 8 contiguous channels ----
__global__ __launch_bounds__(256) void norm1_kernel(const float* __restrict__ x,
                                                    const float* __restrict__ w,
                                                    const float* __restrict__ bvec,
                                                    bf16_t* __restrict__ h) {
  const int wv = threadIdx.x >> 6, l = threadIdx.x & 63;
  const long tok = (long)blockIdx.x * 4 + wv;
  const int c0 = l * 8;
  const f32x4 a = *(const f32x4*)(x + tok * CC + c0);
  const f32x4 b = *(const f32x4*)(x + tok * CC + c0 + 4);
  float v[8];
#pragma unroll
  for (int i = 0; i < 4; ++i) { v[i] = a[i]; v[4 + i] = b[i]; }
  float s = 0.f, s2 = 0.f;
#pragma unroll
  for (int i = 0; i < 8; ++i) { s += v[i]; s2 += v[i] * v[i]; }
  for (int off = 32; off; off >>= 1) { s += __shfl_xor(s, off); s2 += __shfl_xor(s2, off); }
  const float mean = s * (1.f / CC);
  const float var  = fmaxf(s2 * (1.f / CC) - mean * mean, 0.f);
  const float rstd = rsqrtf(var + 1e-5f);
  const f32x4 w0 = *(const f32x4*)(w + c0), w1 = *(const f32x4*)(w + c0 + 4);
  const f32x4 b0 = *(const f32x4*)(bvec + c0), b1 = *(const f32x4*)(bvec + c0 + 4);
  bf16x8 o;
#pragma unroll
  for (int i = 0; i < 4; ++i) {
    o[i]     = (bf16_t)(w0[i] * (v[i] - mean) * rstd + b0[i]);
    o[4 + i] = (bf16_t)(w1[i] * (v[4 + i] - mean) * rstd + b1[i]);
  }
  *(bf16x8*)(h + tok * CC + c0) = o;
}

// ---- kv partial: block = (b,head,chunk of 256 tokens) ----
__global__ __launch_bounds__(256) void kv_partial_kernel(const bf16_t* __restrict__ h,
                                                         const float* __restrict__ klw,
                                                         const float* __restrict__ klb,
                                                         const float* __restrict__ vlw,
                                                         const float* __restrict__ vlb,
                                                         float* __restrict__ kvp) {
  __shared__ bf16_t kb[256 * 32];
  __shared__ bf16_t vb[256 * 32];
  __shared__ float scratch[192 * 16];   // 12KB
  const int tid = threadIdx.x;
  const int bh = blockIdx.x >> 6, chunk = blockIdx.x & 63;
  const int head = bh & 15;
  const int b = bh >> 4;
  const long tok0 = ((long)b << 14) + chunk * 256;
  const bf16_t* src = h + (tok0 + tid) * (long)CC + head * DD;
  float hv[32];
  {
    float s = 0.f, s2 = 0.f;
#pragma unroll
    for (int c = 0; c < 4; ++c) {
      const bf16x8 r = *(const bf16x8*)(src + c * 8);
#pragma unroll
      for (int j = 0; j < 8; ++j) {
        hv[c * 8 + j] = (float)r[j]; s += hv[c * 8 + j]; s2 += hv[c * 8 + j] * hv[c * 8 + j];
      }
    }
    const float mean = s * (1.f / 32.f);
    const float varu = fmaxf((s2 - 32.f * mean * mean) * (1.f / 31.f), 0.f);
    const float inv = 1.f / (sqrtf(varu) + 1e-5f);   // torch.std semantics
    const int sx = (tid >> 1) & 3;
#pragma unroll
    for (int c = 0; c < 4; ++c) {
      bf16x8 kc, vc;
#pragma unroll
      for (int j = 0; j < 8; ++j) {
        const int d = c * 8 + j;
        const float t = (hv[d] - mean) * inv;
        kc[j] = (bf16_t)(klw[head * DD + d] * t + klb[head * DD + d]);
        vc[j] = (bf16_t)(vlw[head * DD + d] * t + vlb[head * DD + d]);
      }
      *(bf16x8*)((char*)kb + tid * 64 + ((c ^ sx) * 16)) = kc;
      *(bf16x8*)((char*)vb + tid * 64 + ((c ^ sx) * 16)) = vc;
    }
  }
  __syncthreads();
  const int g = tid >> 6, l = tid & 63;
  const int d0 = (l >> 3) * 4, e0 = (l & 7) * 4;
  const int ck = (l >> 3) >> 1, hk = (l >> 3) & 1;
  const int ce = (l & 7) >> 1, he = l & 1;
  float a[4][4] = {};
  for (int t = g; t < 256; t += 4) {
    const int tx = (t >> 1) & 3;
    const bf16x4 kq = *(const bf16x4*)((const char*)kb + t * 64 + ((ck ^ tx) * 16) + hk * 8);
    const bf16x4 vq = *(const bf16x4*)((const char*)vb + t * 64 + ((ce ^ tx) * 16) + he * 8);
    float kf[4], vf[4];
#pragma unroll
    for (int i2 = 0; i2 < 4; ++i2) { kf[i2] = (float)kq[i2]; vf[i2] = (float)vq[i2]; }
#pragma unroll
    for (int i2 = 0; i2 < 4; ++i2)
#pragma unroll
      for (int j2 = 0; j2 < 4; ++j2) a[i2][j2] += kf[i2] * vf[j2];
  }
  __syncthreads();
  if (g) {
#pragma unroll
    for (int i2 = 0; i2 < 4; ++i2)
#pragma unroll
      for (int j2 = 0; j2 < 4; ++j2)
        scratch[((g - 1) * 64 + l) * 16 + i2 * 4 + j2] = a[i2][j2];
  }
  __syncthreads();
  if (!g) {
#pragma unroll
    for (int gg = 0; gg < 3; ++gg)
#pragma unroll
      for (int i2 = 0; i2 < 4; ++i2)
#pragma unroll
        for (int j2 = 0; j2 < 4; ++j2)
          a[i2][j2] += scratch[(gg * 64 + l) * 16 + i2 * 4 + j2];
    float* dst = kvp + ((long)(bh * 64 + chunk) << 10);
#pragma unroll
    for (int i2 = 0; i2 < 4; ++i2) {
      f32x4 st;
      st[0] = a[i2][0]; st[1] = a[i2][1]; st[2] = a[i2][2]; st[3] = a[i2][3];
      *(f32x4*)&dst[(d0 + i2) * 32 + e0] = st;
    }
  }
}

// ---- kv reduce over 64 chunks, /N, store TRANSPOSED bf16: kvT[bh][e][d] ----
__global__ __launch_bounds__(256) void kv_reduce_kernel(const float* __restrict__ kvp,
                                                        bf16_t* __restrict__ kvT) {
  const int bh = blockIdx.x;
  const int i4 = threadIdx.x * 4;
  const int d = i4 >> 5, e0 = i4 & 31;
  float s[4] = {};
  const float* p = kvp + ((long)bh << 16) + i4;
  for (int ch = 0; ch < 64; ++ch) {
    const f32x4 t = *(const f32x4*)(p + (ch << 10));
    s[0] += t[0]; s[1] += t[1]; s[2] += t[2]; s[3] += t[3];
  }
  const float sc = 1.f / (float)NN;
  bf16_t* q = kvT + ((long)bh << 10);
#pragma unroll
  for (int j = 0; j < 4; ++j) q[(e0 + j) * 32 + d] = (bf16_t)(s[j] * sc);
}

// ---- fused: MFMA attn + residuals -> x2 (bf16 to ws), LN2 -> m (bf16) ----
#define ASTRIDE 520
__global__ __launch_bounds__(256) void attn_fused_kernel(const float* __restrict__ x,
                                                         const bf16_t* __restrict__ h,
                                                         const bf16_t* __restrict__ kvTg,
                                                         const float* __restrict__ n2w,
                                                         const float* __restrict__ n2b,
                                                         bf16_t* __restrict__ x2b,
                                                         bf16_t* __restrict__ mout) {
  __shared__ bf16_t attn_s[32 * ASTRIDE];
  const int tid = threadIdx.x;
  const int wv = tid >> 6, lane = tid & 63;
  const int lr = lane & 15, kg = lane >> 4;
  const long tok0 = (long)blockIdx.x * 32;
  const int b = (int)(tok0 >> 14);
  const bf16_t* kvsrc = kvTg + ((long)b << 14);

  {
    const int tt = wv & 1, hh = wv >> 1;
    const bf16_t* arow = h + (tok0 + tt * 16 + lr) * (long)CC + kg * 8;
    const f32x4 zero = {};
#pragma unroll
    for (int hi = 0; hi < 8; ++hi) {
      const int hd = hh * 8 + hi;
      const bf16_t* kvh = kvsrc + (hd << 10) + kg * 8;
      const bf16x8 af = *(const bf16x8*)(arow + hd * DD);
      const bf16x8 b0 = *(const bf16x8*)(kvh + lr * 32);
      const bf16x8 b1 = *(const bf16x8*)(kvh + (16 + lr) * 32);
      const f32x4 a0 = __builtin_amdgcn_mfma_f32_16x16x32_bf16(af, b0, zero, 0, 0, 0);
      const f32x4 a1 = __builtin_amdgcn_mfma_f32_16x16x32_bf16(af, b1, zero, 0, 0, 0);
      const int rbase = tt * 16 + kg * 4;
#pragma unroll
      for (int rg = 0; rg < 4; ++rg) {
        attn_s[(rbase + rg) * ASTRIDE + hd * 32 + lr]      = (bf16_t)a0[rg];
        attn_s[(rbase + rg) * ASTRIDE + hd * 32 + 16 + lr] = (bf16_t)a1[rg];
      }
    }
  }

  const int c0 = lane * 8;
  const f32x4 w0 = *(const f32x4*)(n2w + c0), w1 = *(const f32x4*)(n2w + c0 + 4);
  const f32x4 bb0 = *(const f32x4*)(n2b + c0), bb1 = *(const f32x4*)(n2b + c0 + 4);

  // preload it=0 BEFORE the barrier (independent of attn_s)
  const long tokp = tok0 + wv * 8;
  f32x4 xa = *(const f32x4*)(x + tokp * CC + c0);
  f32x4 xb = *(const f32x4*)(x + tokp * CC + c0 + 4);
  bf16x8 hv = *(const bf16x8*)(h + tokp * CC + c0);
  __syncthreads();

#pragma unroll
  for (int it = 0; it < 8; ++it) {
    const int tl = wv * 8 + it;
    const long tok = tok0 + tl;
    f32x4 xa1, xb1;
    bf16x8 hv1;
    if (it < 7) {
      xa1 = *(const f32x4*)(x + (tok + 1) * CC + c0);
      xb1 = *(const f32x4*)(x + (tok + 1) * CC + c0 + 4);
      hv1 = *(const bf16x8*)(h + (tok + 1) * CC + c0);
    }
    const bf16x8 av = *(const bf16x8*)&attn_s[tl * ASTRIDE + c0];
    float x2[8];
#pragma unroll
    for (int i = 0; i < 4; ++i) {
      x2[i]     = xa[i] + (float)hv[i]     + (float)av[i];
      x2[4 + i] = xb[i] + (float)hv[4 + i] + (float)av[4 + i];
    }
    float s = 0.f, s2 = 0.f;
#pragma unroll
    for (int i = 0; i < 8; ++i) { s += x2[i]; s2 += x2[i] * x2[i]; }
    for (int off = 32; off; off >>= 1) { s += __shfl_xor(s, off); s2 += __shfl_xor(s2, off); }
    const float mean = s * (1.f / CC);
    const float var  = fmaxf(s2 * (1.f / CC) - mean * mean, 0.f);
    const float rstd = rsqrtf(var + 1e-5f);
    bf16x8 ox, om;
#pragma unroll
    for (int i = 0; i < 4; ++i) {
      ox[i]     = (bf16_t)x2[i];
      ox[4 + i] = (bf16_t)x2[4 + i];
      om[i]     = (bf16_t)(w0[i] * (x2[i] - mean) * rstd + bb0[i]);
      om[4 + i] = (bf16_t)(w1[i] * (x2[4 + i] - mean) * rstd + bb1[i]);
    }
    *(bf16x8*)(x2b + tok * CC + c0) = ox;
    *(bf16x8*)(mout + tok * CC + c0) = om;
    xa = xa1; xb = xb1; hv = hv1;
  }
}

// ---- 8-phase GEMM (r16 schedule, session best) with 32x32x16 MFMA ----
template <int K, int NOUT, int BN, bool GELU>
__global__ __launch_bounds__(512, 2) void gemm8p_kernel(const bf16_t* __restrict__ A,
                                                        const bf16_t* __restrict__ Bw,
                                                        const float* __restrict__ bias,
                                                        bf16_t* __restrict__ outb,
                                                        float* __restrict__ outf,
                                                        const bf16_t* __restrict__ x2b) {
  constexpr int NTILE = NOUT / BN;
  constexpr int NT = K / 64;                 // K-tiles
  constexpr int NI = NT / 2;                 // iterations (2 K-tiles each)
  constexpr int WNSPAN = BN / 4;             // wave N span (64 or 32)
  constexpr int NF2 = WNSPAN / 32;           // 32-wide N frags per wave (2 or 1)
  constexpr int BLOADS = BN / 128;           // B loads per ks-unit (2 or 1)
  constexpr int ABYT = 32768;                // A bytes per buffer
  constexpr int BBYT = BN * 128;             // B bytes per buffer
  constexpr int BUFB = ABYT + BBYT;
  constexpr int KSB = BN * 64;               // B kslice stride (bytes)

  __shared__ char lds[2 * BUFB];

  const int tid = threadIdx.x;
  const int wid = tid >> 6, lane = tid & 63;
  const int wm = wid >> 2, wn = wid & 3;
  const int l31 = lane & 31, kg5 = lane >> 5;

  int bid = blockIdx.x;
  const int qq = gridDim.x >> 3;
  bid = (bid & 7) * qq + (bid >> 3);        // XCD swizzle (grid % 8 == 0)
  const long row0 = (long)(bid / NTILE) * 256;
  const long col0 = (long)(bid % NTILE) * BN;

  const int srow = tid >> 2;                                   // 0..127
  const int ssw = (((srow >> 1) & 3) ^ ((srow >> 3) & 3));     // enriched swizzle
  const int sce = (((tid & 3) ^ ssw) << 3);                    // pre-swizzled col
  const bf16_t* pA = A + (row0 + srow) * (long)K + sce;
  const bf16_t* pB = Bw + (col0 + srow) * (long)K + sce;
  char* ldsp = (char*)lds;

  auto SA = [&](int buf, int ks, int kt) {
    char* d_ = ldsp + buf * BUFB + ks * 16384 + tid * 16;
    const bf16_t* g_ = pA + (long)kt * 64 + ks * 32;
    gload_lds16(g_, d_);
    gload_lds16(g_ + 128L * K, d_ + 8192);
  };
  auto SB = [&](int buf, int ks, int kt) {
    char* d_ = ldsp + buf * BUFB + ABYT + ks * KSB + tid * 16;
    const bf16_t* g_ = pB + (long)kt * 64 + ks * 32;
    gload_lds16(g_, d_);
    if constexpr (BLOADS == 2) gload_lds16(g_ + 128L * K, d_ + 8192);
  };

  f32x16 acc[4][NF2] = {};
  bf16x8 af[4], bf[NF2];

  const int swz = ((l31 >> 1) & 3) ^ ((l31 >> 3) & 3);
  const int cb0 = (((0 << 1) | kg5) ^ swz) << 4;
  const int cb1 = (((1 << 1) | kg5) ^ swz) << 4;
  const char* aR = ldsp + (wm * 128 + l31) * 64;
  const char* bR = ldsp + ABYT + (wn * WNSPAN + l31) * 64;

  auto RD = [&](int buf, int ks, int k16) {
    const int cb = k16 ? cb1 : cb0;
    const char* a_ = aR + buf * BUFB + ks * 16384 + cb;
    const char* b_ = bR + buf * BUFB + ks * KSB + cb;
#pragma unroll
    for (int mf = 0; mf < 4; ++mf) af[mf] = *(const bf16x8*)(a_ + mf * 2048);
#pragma unroll
    for (int nf = 0; nf < NF2; ++nf) bf[nf] = *(const bf16x8*)(b_ + nf * 2048);
  };
  auto MM = [&]() {
    __builtin_amdgcn_s_setprio(1);
#pragma unroll
    for (int mf = 0; mf < 4; ++mf)
#pragma unroll
      for (int nf = 0; nf < NF2; ++nf)
        acc[mf][nf] =
            __builtin_amdgcn_mfma_f32_32x32x16_bf16(af[mf], bf[nf], acc[mf][nf], 0, 0, 0);
    __builtin_amdgcn_s_setprio(0);
  };
  auto W2U = [&]() {
    if constexpr (BLOADS == 2) asm volatile("s_waitcnt vmcnt(8)" ::: "memory");
    else                       asm volatile("s_waitcnt vmcnt(6)" ::: "memory");
  };
  auto W1U = [&]() {
    if constexpr (BLOADS == 2) asm volatile("s_waitcnt vmcnt(4)" ::: "memory");
    else                       asm volatile("s_waitcnt vmcnt(3)" ::: "memory");
  };
#define BARX() __builtin_amdgcn_s_barrier()
#define LGKM0() asm volatile("s_waitcnt lgkmcnt(0)" ::: "memory")
#define W0U() asm volatile("s_waitcnt vmcnt(0)" ::: "memory")

  // prologue: stage 3 units in consumption order; land unit 1 only
  SA(0, 0, 0); SB(0, 0, 0);
  SA(0, 1, 0); SB(0, 1, 0);
  SA(1, 0, 1); SB(1, 0, 1);
  W2U();
  BARX();

  for (int i = 0; i < NI; ++i) {
    const int t1 = 2 * i + 1, tA = 2 * i + 2, tB = 2 * i + 3;
    // p1: read b0.ks0.k0 | stage b1k1.A
    RD(0, 0, 0); SA(1, 1, t1);
    BARX(); LGKM0(); MM(); BARX();
    // p2: read b0.ks0.k1 | stage b1k1.B | wait lands b0k1 (for p3/p4)
    RD(0, 0, 1); SB(1, 1, t1);
    BARX(); LGKM0(); MM(); W2U(); BARX();
    // p3: read b0.ks1.k0 | stage next b0k0.A
    RD(0, 1, 0); if (tA < NT) SA(0, 0, tA);
    BARX(); LGKM0(); MM(); BARX();
    // p4: read b0.ks1.k1 | stage next b0k0.B | wait lands b1k0 (for p5/p6)
    RD(0, 1, 1); if (tA < NT) SB(0, 0, tA);
    BARX(); LGKM0(); MM();
    if (tA < NT) W2U(); else W1U();
    BARX();
    // p5: read b1.ks0.k0 | stage next b0k1.A
    RD(1, 0, 0); if (tA < NT) SA(0, 1, tA);
    BARX(); LGKM0(); MM(); BARX();
    // p6: read b1.ks0.k1 | stage next b0k1.B | wait lands b1k1 (for p7/p8)
    RD(1, 0, 1); if (tA < NT) SB(0, 1, tA);
    BARX(); LGKM0(); MM();
    if (tA < NT) W2U(); else W0U();
    BARX();
    // p7: read b1.ks1.k0 | stage next b1k0.A
    RD(1, 1, 0); if (tB < NT) SA(1, 0, tB);
    BARX(); LGKM0(); MM(); BARX();
    // p8: read b1.ks1.k1 | stage next b1k0.B | wait lands next b0k0
    RD(1, 1, 1); if (tB < NT) SB(1, 0, tB);
    BARX(); LGKM0(); MM();
    if (tB < NT) W2U();
    BARX();
  }
#undef BARX
#undef LGKM0
#undef W0U

  // epilogue: 32x32 C/D layout: col = l31, row = (r&3) + 8*(r>>2) + 4*kg5
#pragma unroll
  for (int mf = 0; mf < 4; ++mf) {
#pragma unroll
    for (int nf = 0; nf < NF2; ++nf) {
      const long col = col0 + wn * WNSPAN + nf * 32 + l31;
      const float bs = bias[col];
#pragma unroll
      for (int r = 0; r < 16; ++r) {
        const long row = row0 + wm * 128 + mf * 32 + (r & 3) + 8 * (r >> 2) + 4 * kg5;
        const float v = acc[mf][nf][r] + bs;
        if constexpr (GELU) {
          const float u = 0.7978845608028654f * (v + 0.044715f * v * v * v);
          const float gv = v / (1.f + __expf(-2.f * u));
          outb[row * NOUT + col] = (bf16_t)gv;
        } else {
          // pure store: final out = x2 + mlp (x2 read back as bf16 from ws)
          outf[row * NOUT + col] = (float)x2b[row * NOUT + col] + v;
        }
      }
    }
  }
}

extern "C" void kernel_launch(void* const* d_in, const int* in_sizes, int n_in,
                              void* d_out, int out_size, void* d_ws, size_t ws_size,
                              hipStream_t stream) {
  const float* x   = (const float*)d_in[0];
  const float* n1w = (const float*)d_in[2];
  const float* n1b = (const float*)d_in[3];
  const float* klw = (const float*)d_in[4];
  const float* klb = (const float*)d_in[5];
  const float* vlw = (const float*)d_in[6];
  const float* vlb = (const float*)d_in[7];
  const float* n2w = (const float*)d_in[8];
  const float* n2b = (const float*)d_in[9];
  const float* w1f = (const float*)d_in[10];
  const float* b1  = (const float*)d_in[11];
  const float* w2f = (const float*)d_in[12];
  const float* b2  = (const float*)d_in[13];
  float* out = (float*)d_out;

  // nch=2: act chunk = 128MB -> L3-resident between GEMM1 and GEMM2
  int nch;
  if (ws_size >= 360000000ULL) nch = 2;
  else                         nch = 4;
  const long mch = MTOT / nch;

  char* ws = (char*)d_ws;
  size_t off = 0;
  bf16_t* h   = (bf16_t*)(ws + off); off += (size_t)MTOT * CC * 2;      // 64 MiB
  bf16_t* mb  = (bf16_t*)(ws + off); off += (size_t)MTOT * CC * 2;      // 64 MiB
  bf16_t* x2b = (bf16_t*)(ws + off); off += (size_t)MTOT * CC * 2;      // 64 MiB
  bf16_t* act = (bf16_t*)(ws + off); off += (size_t)mch * HID * 2;      // 256/nch MiB
  bf16_t* w1  = (bf16_t*)(ws + off); off += (size_t)HID * CC * 2;       // 2 MiB
  bf16_t* w2  = (bf16_t*)(ws + off); off += (size_t)HID * CC * 2;       // 2 MiB
  float*  kvp = (float*)(ws + off);  off += (size_t)BB * HH * 64 * 1024 * 4; // 16 MiB
  bf16_t* kvT = (bf16_t*)(ws + off);                                    // 128 KiB

  cvt_bf16_kernel<<<1024, 256, 0, stream>>>(w1f, w1);
  cvt_bf16_kernel<<<1024, 256, 0, stream>>>(w2f, w2);
  norm1_kernel<<<MTOT / 4, 256, 0, stream>>>(x, n1w, n1b, h);
  kv_partial_kernel<<<BB * HH * 64, 256, 0, stream>>>(h, klw, klb, vlw, vlb, kvp);
  kv_reduce_kernel<<<BB * HH, 256, 0, stream>>>(kvp, kvT);
  attn_fused_kernel<<<MTOT / 32, 256, 0, stream>>>(x, h, kvT, n2w, n2b, x2b, mb);
  for (int ch = 0; ch < nch; ++ch) {
    gemm8p_kernel<CC, HID, 256, true>
        <<<(int)((mch / 256) * (HID / 256)), 512, 0, stream>>>(
        mb + (size_t)ch * mch * CC, w1, b1, act, nullptr, nullptr);
    if (mch >= 32768) {
      gemm8p_kernel<HID, CC, 256, false>
          <<<(int)((mch / 256) * (CC / 256)), 512, 0, stream>>>(
          act, w2, b2, nullptr, out + (size_t)ch * mch * CC,
          x2b + (size_t)ch * mch * CC);
    } else {
      gemm8p_kernel<HID, CC, 128, false>
          <<<(int)((mch / 256) * (CC / 128)), 512, 0, stream>>>(
          act, w2, b2, nullptr, out + (size_t)ch * mch * CC,
          x2b + (size_t)ch * mch * CC);
    }
  }
}